// Round 8
// baseline (173.037 us; speedup 1.0000x reference)
//
#include <hip/hip_runtime.h>
#include <cstddef>

#define HH 224
#define WW 608
#define HWSZ (HH * WW)

__device__ __forceinline__ float lrelu(float v) { return v > 0.0f ? v : 0.01f * v; }

// CondMul, output dim split across a 4-lane group (sub-lane s).
// Weight layout [i=0..31][o=0..CO-1] (wmat already offset by the gather index).
// Activations distributed 8/lane; lane sp holds act[ii] = x[8*sp+ii].
// Accumulation: i ascending per output, bias last — matches reference order.
template <int CO>
__device__ __forceinline__ void cm4(const float* __restrict__ wmat,
                                    const float* __restrict__ bvec,
                                    int s, const float (&act)[8], float (&acc)[CO / 4]) {
    constexpr int CH = CO / 4;
#pragma unroll
    for (int j = 0; j < CH; j++) acc[j] = 0.0f;
#pragma unroll
    for (int sp = 0; sp < 4; sp++) {
#pragma unroll
        for (int ii = 0; ii < 8; ii++) {
            float xi = __shfl(act[ii], sp, 4);
            const float* wr = wmat + (sp * 8 + ii) * CO + s * CH;
            if constexpr (CH == 8) {
                float4 a = *reinterpret_cast<const float4*>(wr);
                float4 b = *reinterpret_cast<const float4*>(wr + 4);
                acc[0] = fmaf(xi, a.x, acc[0]); acc[1] = fmaf(xi, a.y, acc[1]);
                acc[2] = fmaf(xi, a.z, acc[2]); acc[3] = fmaf(xi, a.w, acc[3]);
                acc[4] = fmaf(xi, b.x, acc[4]); acc[5] = fmaf(xi, b.y, acc[5]);
                acc[6] = fmaf(xi, b.z, acc[6]); acc[7] = fmaf(xi, b.w, acc[7]);
            } else {
                float4 a = *reinterpret_cast<const float4*>(wr);
                acc[0] = fmaf(xi, a.x, acc[0]); acc[1] = fmaf(xi, a.y, acc[1]);
                acc[2] = fmaf(xi, a.z, acc[2]); acc[3] = fmaf(xi, a.w, acc[3]);
            }
        }
    }
#pragma unroll
    for (int j = 0; j < CH; j++) acc[j] += bvec[s * CH + j];
}

__device__ __forceinline__ void wb_lrelu8(float (&act)[8], const float (&acc)[8]) {
#pragma unroll
    for (int j = 0; j < 8; j++) act[j] = lrelu(acc[j]);
}

__device__ __forceinline__ int argmax4(const float (&v)[4], int s) {
    float bv = v[0];
    int bi = 4 * s;
#pragma unroll
    for (int j = 1; j < 4; j++) {
        if (v[j] > bv) { bv = v[j]; bi = 4 * s + j; }
    }
#pragma unroll
    for (int m = 1; m <= 2; m <<= 1) {
        float ov = __shfl_xor(bv, m, 4);
        int oi = __shfl_xor(bi, m, 4);
        if (ov > bv || (ov == bv && oi < bi)) { bv = ov; bi = oi; }
    }
    return bi;
}

// ================= K1: stage 1 (per-line MLP, LDS weights) -> c1 =================
extern "C" __global__ __launch_bounds__(256, 4)
void k_stage1(const float* __restrict__ x_in,
              const float* __restrict__ w1_0, const float* __restrict__ b1_0,
              const float* __restrict__ w1_1, const float* __restrict__ b1_1,
              const float* __restrict__ w1_2, const float* __restrict__ b1_2,
              int* __restrict__ c1out) {
    const int h = blockIdx.y;
    const int tid = threadIdx.x;
    const int p = tid >> 2;
    const int s = tid & 3;
    const int w = blockIdx.x * 64 + p;
    const bool valid = (w < WW);
    const int wc = valid ? w : (WW - 1);
    const int base = h * WW + wc;

    __shared__ __align__(16) float sW0[1024];
    __shared__ __align__(16) float sW1[1024];
    __shared__ __align__(16) float sW2[512];
    for (int tt = tid; tt < 1024; tt += 256) {
        int i = tt >> 5, o = tt & 31;
        sW0[tt] = w1_0[h * 1024 + o * 32 + i];
        sW1[tt] = w1_1[h * 1024 + o * 32 + i];
    }
    for (int tt = tid; tt < 512; tt += 256) {
        int i = tt >> 4, o = tt & 15;
        sW2[tt] = w1_2[h * 512 + o * 32 + i];
    }
    __syncthreads();

    float act[8], acc8[8], acc4[4];
#pragma unroll
    for (int ii = 0; ii < 8; ii++) act[ii] = x_in[(8 * s + ii) * HWSZ + base];
    cm4<32>(sW0, b1_0 + h * 32, s, act, acc8);
    wb_lrelu8(act, acc8);
    cm4<32>(sW1, b1_1 + h * 32, s, act, acc8);
    wb_lrelu8(act, acc8);
    cm4<16>(sW2, b1_2 + h * 16, s, act, acc4);
    const int i1 = argmax4(acc4, s);

    if (s == 0 && valid) c1out[base] = i1;
}

// == K2/K4: per-line counting sort by class + permuted (sorted-order) copy of x ==
// Emits: perm[pos]=w, raw_sorted[pos]=raw class, xs[ch][pos]=x[CH0+ch][perm[pos]].
// Any permutation is valid (pixels independent) -> atomic nondeterminism cannot
// affect d_out. Scattered reads stay within one line's 2.4KB span (L1-resident);
// all global writes are coalesced.
template <int NBINS, int CH0, int NCH>
__global__ __launch_bounds__(1024)
void k_sort_copy(const float* __restrict__ x_in,
                 const int* __restrict__ cls_in, int clipmax,
                 int* __restrict__ perm, int* __restrict__ raw_sorted,
                 float* __restrict__ xs) {
    const int h = blockIdx.x;
    const int tid = threadIdx.x;
    __shared__ int raw[WW];
    __shared__ int cclip[WW];
    __shared__ int perml[WW];
    __shared__ int hist[NBINS];
    __shared__ int off[NBINS];
    for (int t = tid; t < NBINS; t += 1024) hist[t] = 0;
    __syncthreads();
    for (int t = tid; t < WW; t += 1024) {
        int v = cls_in[h * WW + t];
        raw[t] = v;
        int c = min(max(v, 0), clipmax);
        cclip[t] = c;
        atomicAdd(&hist[c], 1);
    }
    __syncthreads();
    if (tid == 0) {
        int run = 0;
        for (int i = 0; i < NBINS; i++) { off[i] = run; run += hist[i]; }
    }
    __syncthreads();
    for (int t = tid; t < WW; t += 1024) {
        int pos = atomicAdd(&off[cclip[t]], 1);
        perml[pos] = t;
    }
    __syncthreads();
    for (int t = tid; t < WW; t += 1024) {
        perm[h * WW + t] = perml[t];
        raw_sorted[h * WW + t] = raw[perml[t]];
    }
    for (int idx = tid; idx < NCH * WW; idx += 1024) {
        int ch = idx / WW;
        int pos = idx - ch * WW;
        xs[(size_t)ch * HWSZ + h * WW + pos] =
            x_in[(size_t)(CH0 + ch) * HWSZ + h * WW + perml[pos]];
    }
}

// ====== K3: stage 2 in class1-sorted order (coalesced xs2) -> inds12[pixel] ======
extern "C" __global__ __launch_bounds__(256, 4)
void k_stage2(const float* __restrict__ xs2,
              const float* __restrict__ w2_0, const float* __restrict__ b2_0,
              const float* __restrict__ w2_1, const float* __restrict__ b2_1,
              const float* __restrict__ w2_2, const float* __restrict__ b2_2,
              const int* __restrict__ c1s, const int* __restrict__ perm1,
              int* __restrict__ inds12out) {
    const int h = blockIdx.y;
    const int tid = threadIdx.x;
    const int s = tid & 3;
    int pos = blockIdx.x * 64 + (tid >> 2);
    pos = min(pos, WW - 1);                 // tail: duplicate of last sorted slot
    const int spos = h * WW + pos;
    const int i1 = c1s[spos];

    float act[8], acc8[8], acc4[4];
#pragma unroll
    for (int ii = 0; ii < 8; ii++) act[ii] = xs2[(size_t)(8 * s + ii) * HWSZ + spos];
    const size_t idx2 = (size_t)h * 16 + (size_t)i1;
    cm4<32>(w2_0 + idx2 * 1024, b2_0 + idx2 * 32, s, act, acc8);
    wb_lrelu8(act, acc8);
    cm4<32>(w2_1 + idx2 * 1024, b2_1 + idx2 * 32, s, act, acc8);
    wb_lrelu8(act, acc8);
    cm4<16>(w2_2 + idx2 * 512, b2_2 + idx2 * 16, s, act, acc4);
    const int i2 = argmax4(acc4, s);

    if (s == 0) inds12out[h * WW + perm1[spos]] = i1 * 12 + (i2 - 2);   // unclipped
}

// == K5: stage 3 + regressor in class12-sorted order (coalesced xs3) -> out ==
extern "C" __global__ __launch_bounds__(256, 4)
void k_stage3(const float* __restrict__ xs3,
              const float* __restrict__ w3_0, const float* __restrict__ b3_0,
              const float* __restrict__ w3_1, const float* __restrict__ b3_1,
              const float* __restrict__ w3_2, const float* __restrict__ b3_2,
              const float* __restrict__ wr0, const float* __restrict__ br0,
              const float* __restrict__ wr1, const float* __restrict__ br1,
              const int* __restrict__ r12s, const int* __restrict__ perm2,
              float* __restrict__ out) {
    const int h = blockIdx.y;
    const int tid = threadIdx.x;
    const int s = tid & 3;
    int pos = blockIdx.x * 64 + (tid >> 2);
    pos = min(pos, WW - 1);
    const int spos = h * WW + pos;
    const int inds12 = r12s[spos];
    const int c12 = min(max(inds12, 0), 191);
    const size_t idx3 = (size_t)h * 192 + (size_t)c12;

    float act[8], acc8[8], acc4[4];
#pragma unroll
    for (int ii = 0; ii < 8; ii++) act[ii] = xs3[(size_t)(8 * s + ii) * HWSZ + spos];
    cm4<32>(w3_0 + idx3 * 1024, b3_0 + idx3 * 32, s, act, acc8);
    wb_lrelu8(act, acc8);
    cm4<32>(w3_1 + idx3 * 1024, b3_1 + idx3 * 32, s, act, acc8);
    wb_lrelu8(act, acc8);
    cm4<16>(w3_2 + idx3 * 512, b3_2 + idx3 * 16, s, act, acc4);
    const int i3 = argmax4(acc4, s);

    const int inds123 = min(max(inds12 * 10 + (i3 - 3), 0), 1919);

#pragma unroll
    for (int ii = 0; ii < 8; ii++) act[ii] = xs3[(size_t)(32 + 8 * s + ii) * HWSZ + spos];
    const size_t idxs = (size_t)h * 384 + (size_t)(inds123 / 5);
    cm4<32>(wr0 + idxs * 1024, br0 + idxs * 32, s, act, acc8);
    wb_lrelu8(act, acc8);

    const size_t idxr = (size_t)h * 1920 + (size_t)inds123;
    const float* __restrict__ wr1r = wr1 + idxr * 32 + 8 * s;
    float4 wa = *reinterpret_cast<const float4*>(wr1r);
    float4 wb = *reinterpret_cast<const float4*>(wr1r + 4);
    float rpart = 0.0f;
    rpart = fmaf(act[0], wa.x, rpart); rpart = fmaf(act[1], wa.y, rpart);
    rpart = fmaf(act[2], wa.z, rpart); rpart = fmaf(act[3], wa.w, rpart);
    rpart = fmaf(act[4], wb.x, rpart); rpart = fmaf(act[5], wb.y, rpart);
    rpart = fmaf(act[6], wb.z, rpart); rpart = fmaf(act[7], wb.w, rpart);
    rpart += __shfl_xor(rpart, 1, 4);
    rpart += __shfl_xor(rpart, 2, 4);
    const float r = rpart + br1[idxr];

    if (s == 0) {
        float v = ((float)inds123 + r) * (1.0f / 1920.0f);
        out[h * WW + perm2[spos]] = (v - 0.1f) * 1.25f;
    }
}

// =============== Fallback: proven monolithic kernel (R6, 135 us) ===============
extern "C" __global__ __launch_bounds__(256, 4)
void regressor_fused(const float* __restrict__ x_in,
                     const float* __restrict__ w1_0, const float* __restrict__ b1_0,
                     const float* __restrict__ w1_1, const float* __restrict__ b1_1,
                     const float* __restrict__ w1_2, const float* __restrict__ b1_2,
                     const float* __restrict__ w2_0, const float* __restrict__ b2_0,
                     const float* __restrict__ w2_1, const float* __restrict__ b2_1,
                     const float* __restrict__ w2_2, const float* __restrict__ b2_2,
                     const float* __restrict__ w3_0, const float* __restrict__ b3_0,
                     const float* __restrict__ w3_1, const float* __restrict__ b3_1,
                     const float* __restrict__ w3_2, const float* __restrict__ b3_2,
                     const float* __restrict__ wr0, const float* __restrict__ br0,
                     const float* __restrict__ wr1, const float* __restrict__ br1,
                     float* __restrict__ out) {
    const int h = blockIdx.y;
    const int tid = threadIdx.x;
    const int p = tid >> 2;
    const int s = tid & 3;
    const int w = blockIdx.x * 64 + p;
    const bool valid = (w < WW);
    const int wc = valid ? w : (WW - 1);
    const int base = h * WW + wc;

    __shared__ __align__(16) float sW0[1024];
    __shared__ __align__(16) float sW1[1024];
    __shared__ __align__(16) float sW2[512];
    for (int tt = tid; tt < 1024; tt += 256) {
        int i = tt >> 5, o = tt & 31;
        sW0[tt] = w1_0[h * 1024 + o * 32 + i];
        sW1[tt] = w1_1[h * 1024 + o * 32 + i];
    }
    for (int tt = tid; tt < 512; tt += 256) {
        int i = tt >> 4, o = tt & 15;
        sW2[tt] = w1_2[h * 512 + o * 32 + i];
    }
    __syncthreads();

    float act[8], acc8[8], acc4[4];
#pragma unroll
    for (int ii = 0; ii < 8; ii++) act[ii] = x_in[(8 * s + ii) * HWSZ + base];
    cm4<32>(sW0, b1_0 + h * 32, s, act, acc8);
    wb_lrelu8(act, acc8);
    cm4<32>(sW1, b1_1 + h * 32, s, act, acc8);
    wb_lrelu8(act, acc8);
    cm4<16>(sW2, b1_2 + h * 16, s, act, acc4);
    const int i1 = argmax4(acc4, s);

#pragma unroll
    for (int ii = 0; ii < 8; ii++) act[ii] = x_in[(32 + 8 * s + ii) * HWSZ + base];
    const size_t idx2 = (size_t)h * 16 + (size_t)i1;
    cm4<32>(w2_0 + idx2 * 1024, b2_0 + idx2 * 32, s, act, acc8);
    wb_lrelu8(act, acc8);
    cm4<32>(w2_1 + idx2 * 1024, b2_1 + idx2 * 32, s, act, acc8);
    wb_lrelu8(act, acc8);
    cm4<16>(w2_2 + idx2 * 512, b2_2 + idx2 * 16, s, act, acc4);
    const int i2 = argmax4(acc4, s);

    const int inds12 = i1 * 12 + (i2 - 2);
    const int c12 = min(max(inds12, 0), 191);
    const size_t idx3 = (size_t)h * 192 + (size_t)c12;

#pragma unroll
    for (int ii = 0; ii < 8; ii++) act[ii] = x_in[(64 + 8 * s + ii) * HWSZ + base];
    cm4<32>(w3_0 + idx3 * 1024, b3_0 + idx3 * 32, s, act, acc8);
    wb_lrelu8(act, acc8);
    cm4<32>(w3_1 + idx3 * 1024, b3_1 + idx3 * 32, s, act, acc8);
    wb_lrelu8(act, acc8);
    cm4<16>(w3_2 + idx3 * 512, b3_2 + idx3 * 16, s, act, acc4);
    const int i3 = argmax4(acc4, s);

    const int inds123 = min(max(inds12 * 10 + (i3 - 3), 0), 1919);

#pragma unroll
    for (int ii = 0; ii < 8; ii++) act[ii] = x_in[(96 + 8 * s + ii) * HWSZ + base];
    const size_t idxs = (size_t)h * 384 + (size_t)(inds123 / 5);
    cm4<32>(wr0 + idxs * 1024, br0 + idxs * 32, s, act, acc8);
    wb_lrelu8(act, acc8);

    const size_t idxr = (size_t)h * 1920 + (size_t)inds123;
    const float* __restrict__ wr1r = wr1 + idxr * 32 + 8 * s;
    float4 wa = *reinterpret_cast<const float4*>(wr1r);
    float4 wb = *reinterpret_cast<const float4*>(wr1r + 4);
    float rpart = 0.0f;
    rpart = fmaf(act[0], wa.x, rpart); rpart = fmaf(act[1], wa.y, rpart);
    rpart = fmaf(act[2], wa.z, rpart); rpart = fmaf(act[3], wa.w, rpart);
    rpart = fmaf(act[4], wb.x, rpart); rpart = fmaf(act[5], wb.y, rpart);
    rpart = fmaf(act[6], wb.z, rpart); rpart = fmaf(act[7], wb.w, rpart);
    rpart += __shfl_xor(rpart, 1, 4);
    rpart += __shfl_xor(rpart, 2, 4);
    const float r = rpart + br1[idxr];

    if (s == 0 && valid) {
        float v = ((float)inds123 + r) * (1.0f / 1920.0f);
        out[h * WW + w] = (v - 0.1f) * 1.25f;
    }
}

extern "C" void kernel_launch(void* const* d_in, const int* in_sizes, int n_in,
                              void* d_out, int out_size, void* d_ws, size_t ws_size,
                              hipStream_t stream) {
    const float* p[23];
    for (int i = 0; i < 23; i++) p[i] = (const float*)d_in[i];
    float* out = (float*)d_out;

    const size_t N = (size_t)HWSZ;
    const size_t need = (6 + 32 + 64) * N * sizeof(float);   // 6 int + 96 float arrays

    if (ws_size < need) {
        regressor_fused<<<dim3(10, HH), 256, 0, stream>>>(
            p[0], p[1], p[2], p[3], p[4], p[5], p[6],
            p[7], p[8], p[9], p[10], p[11], p[12],
            p[13], p[14], p[15], p[16], p[17], p[18],
            p[19], p[20], p[21], p[22], out);
        return;
    }

    int* c1 = (int*)d_ws;
    int* perm1 = c1 + N;
    int* c1s = perm1 + N;
    int* inds12 = c1s + N;
    int* perm2 = inds12 + N;
    int* r12s = perm2 + N;
    float* xs2 = (float*)(r12s + N);
    float* xs3 = xs2 + 32 * N;

    dim3 gridMain(10, HH);
    k_stage1<<<gridMain, 256, 0, stream>>>(p[0], p[1], p[2], p[3], p[4], p[5], p[6], c1);
    k_sort_copy<16, 32, 32><<<dim3(HH), 1024, 0, stream>>>(p[0], c1, 15, perm1, c1s, xs2);
    k_stage2<<<gridMain, 256, 0, stream>>>(xs2, p[7], p[8], p[9], p[10], p[11], p[12],
                                           c1s, perm1, inds12);
    k_sort_copy<192, 64, 64><<<dim3(HH), 1024, 0, stream>>>(p[0], inds12, 191, perm2, r12s, xs3);
    k_stage3<<<gridMain, 256, 0, stream>>>(xs3, p[13], p[14], p[15], p[16], p[17], p[18],
                                           p[19], p[20], p[21], p[22],
                                           r12s, perm2, out);
}

// Round 9
// 126.259 us; speedup vs baseline: 1.3705x; 1.3705x over previous
//
#include <hip/hip_runtime.h>
#include <cstddef>

#define HH 224
#define WW 608
#define HWSZ (HH * WW)

__device__ __forceinline__ float lrelu(float v) { return v > 0.0f ? v : 0.01f * v; }

// CondMul, output dim split across a 4-lane group (sub-lane s).
// Weight layout [i=0..31][o=0..CO-1] (wmat already offset by the gather index).
// Works identically for global or LDS wmat (inlined -> addrspace inferred).
// Accumulation: i ascending per output, bias last — matches reference order.
template <int CO>
__device__ __forceinline__ void cm4(const float* wmat,
                                    const float* bvec,
                                    int s, const float (&act)[8], float (&acc)[CO / 4]) {
    constexpr int CH = CO / 4;
#pragma unroll
    for (int j = 0; j < CH; j++) acc[j] = 0.0f;
#pragma unroll
    for (int sp = 0; sp < 4; sp++) {
#pragma unroll
        for (int ii = 0; ii < 8; ii++) {
            float xi = __shfl(act[ii], sp, 4);
            const float* wr = wmat + (sp * 8 + ii) * CO + s * CH;
            if constexpr (CH == 8) {
                float4 a = *reinterpret_cast<const float4*>(wr);
                float4 b = *reinterpret_cast<const float4*>(wr + 4);
                acc[0] = fmaf(xi, a.x, acc[0]); acc[1] = fmaf(xi, a.y, acc[1]);
                acc[2] = fmaf(xi, a.z, acc[2]); acc[3] = fmaf(xi, a.w, acc[3]);
                acc[4] = fmaf(xi, b.x, acc[4]); acc[5] = fmaf(xi, b.y, acc[5]);
                acc[6] = fmaf(xi, b.z, acc[6]); acc[7] = fmaf(xi, b.w, acc[7]);
            } else {
                float4 a = *reinterpret_cast<const float4*>(wr);
                acc[0] = fmaf(xi, a.x, acc[0]); acc[1] = fmaf(xi, a.y, acc[1]);
                acc[2] = fmaf(xi, a.z, acc[2]); acc[3] = fmaf(xi, a.w, acc[3]);
            }
        }
    }
#pragma unroll
    for (int j = 0; j < CH; j++) acc[j] += bvec[s * CH + j];
}

__device__ __forceinline__ void wb_lrelu8(float (&act)[8], const float (&acc)[8]) {
#pragma unroll
    for (int j = 0; j < 8; j++) act[j] = lrelu(acc[j]);
}

// First-max argmax over 16 values distributed 4-per-lane across the 4-lane group.
__device__ __forceinline__ int argmax4(const float (&v)[4], int s) {
    float bv = v[0];
    int bi = 4 * s;
#pragma unroll
    for (int j = 1; j < 4; j++) {
        if (v[j] > bv) { bv = v[j]; bi = 4 * s + j; }
    }
#pragma unroll
    for (int m = 1; m <= 2; m <<= 1) {
        float ov = __shfl_xor(bv, m, 4);
        int oi = __shfl_xor(bi, m, 4);
        if (ov > bv || (ov == bv && oi < bi)) { bv = ov; bi = oi; }
    }
    return bi;
}

// Stage NF floats (16B-aligned) into this wave's private LDS slab.
// No __syncthreads needed: slab is wave-private; per-wave DS ops are in-order
// and the compiler inserts the vmcnt/lgkmcnt waits for the load->write->read chain.
template <int NF>
__device__ __forceinline__ void stage_mat(float* ws, const float* __restrict__ src, int lane) {
    const float4* s4 = reinterpret_cast<const float4*>(src);
    float4* w4 = reinterpret_cast<float4*>(ws);
#pragma unroll
    for (int t = 0; t < NF / 4 / 64; t++) w4[t * 64 + lane] = s4[t * 64 + lane];
}

extern "C" __global__ __launch_bounds__(256, 4)
void regressor_fused(const float* __restrict__ x_in,
                     const float* __restrict__ w1_0, const float* __restrict__ b1_0,
                     const float* __restrict__ w1_1, const float* __restrict__ b1_1,
                     const float* __restrict__ w1_2, const float* __restrict__ b1_2,
                     const float* __restrict__ w2_0, const float* __restrict__ b2_0,
                     const float* __restrict__ w2_1, const float* __restrict__ b2_1,
                     const float* __restrict__ w2_2, const float* __restrict__ b2_2,
                     const float* __restrict__ w3_0, const float* __restrict__ b3_0,
                     const float* __restrict__ w3_1, const float* __restrict__ b3_1,
                     const float* __restrict__ w3_2, const float* __restrict__ b3_2,
                     const float* __restrict__ wr0, const float* __restrict__ br0,
                     const float* __restrict__ wr1, const float* __restrict__ br1,
                     float* __restrict__ out) {
    const int h = blockIdx.y;
    const int tid = threadIdx.x;
    const int p = tid >> 2;          // pixel within block (0..63)
    const int s = tid & 3;           // output-chunk sub-lane (0..3)
    const int lane = tid & 63;
    const int w = blockIdx.x * 64 + p;
    const bool valid = (w < WW);
    const int wc = valid ? w : (WW - 1);   // tail lanes compute a duplicate pixel
    const int base = h * WW + wc;

    // ---- stage-1 per-line weights (block-shared, transposed to [i][o]) ----
    __shared__ __align__(16) float sW0[1024];
    __shared__ __align__(16) float sW1[1024];
    __shared__ __align__(16) float sW2[512];
    // ---- wave-private staging slabs for uniform-class CondMuls ----
    __shared__ __align__(16) float sUni[4][1024];
    float* ws = sUni[tid >> 6];

    for (int tt = tid; tt < 1024; tt += 256) {
        int i = tt >> 5, o = tt & 31;
        sW0[tt] = w1_0[h * 1024 + o * 32 + i];
        sW1[tt] = w1_1[h * 1024 + o * 32 + i];
    }
    for (int tt = tid; tt < 512; tt += 256) {
        int i = tt >> 4, o = tt & 15;
        sW2[tt] = w1_2[h * 512 + o * 32 + i];
    }
    __syncthreads();

    float act[8], acc8[8], acc4[4];

    // ---------------- stage 1: per-line MLP -> class1 ----------------
#pragma unroll
    for (int ii = 0; ii < 8; ii++) act[ii] = x_in[(8 * s + ii) * HWSZ + base];
    cm4<32>(sW0, b1_0 + h * 32, s, act, acc8);
    wb_lrelu8(act, acc8);
    cm4<32>(sW1, b1_1 + h * 32, s, act, acc8);
    wb_lrelu8(act, acc8);
    cm4<16>(sW2, b1_2 + h * 16, s, act, acc4);
    const int i1 = argmax4(acc4, s);

    // ---------------- stage 2: CondMul on (line, class1) ----------------
#pragma unroll
    for (int ii = 0; ii < 8; ii++) act[ii] = x_in[(32 + 8 * s + ii) * HWSZ + base];
    {
        const int fi1 = __builtin_amdgcn_readfirstlane(i1);
        if (__all(i1 == fi1)) {
            // whole wave same class: stage each 4KB matrix once, read via LDS broadcast
            const size_t u = (size_t)h * 16 + (size_t)fi1;
            stage_mat<1024>(ws, w2_0 + u * 1024, lane);
            cm4<32>(ws, b2_0 + u * 32, s, act, acc8);
            wb_lrelu8(act, acc8);
            stage_mat<1024>(ws, w2_1 + u * 1024, lane);
            cm4<32>(ws, b2_1 + u * 32, s, act, acc8);
            wb_lrelu8(act, acc8);
            stage_mat<512>(ws, w2_2 + u * 512, lane);
            cm4<16>(ws, b2_2 + u * 16, s, act, acc4);
        } else {
            const size_t idx2 = (size_t)h * 16 + (size_t)i1;
            cm4<32>(w2_0 + idx2 * 1024, b2_0 + idx2 * 32, s, act, acc8);
            wb_lrelu8(act, acc8);
            cm4<32>(w2_1 + idx2 * 1024, b2_1 + idx2 * 32, s, act, acc8);
            wb_lrelu8(act, acc8);
            cm4<16>(w2_2 + idx2 * 512, b2_2 + idx2 * 16, s, act, acc4);
        }
    }
    const int i2 = argmax4(acc4, s);

    const int inds12 = i1 * 12 + (i2 - 2);               // unclipped (used below)
    const int c12 = min(max(inds12, 0), 191);

    // ---------------- stage 3: CondMul on (line, class12) ----------------
#pragma unroll
    for (int ii = 0; ii < 8; ii++) act[ii] = x_in[(64 + 8 * s + ii) * HWSZ + base];
    {
        const int fc12 = __builtin_amdgcn_readfirstlane(c12);
        if (__all(c12 == fc12)) {
            const size_t u = (size_t)h * 192 + (size_t)fc12;
            stage_mat<1024>(ws, w3_0 + u * 1024, lane);
            cm4<32>(ws, b3_0 + u * 32, s, act, acc8);
            wb_lrelu8(act, acc8);
            stage_mat<1024>(ws, w3_1 + u * 1024, lane);
            cm4<32>(ws, b3_1 + u * 32, s, act, acc8);
            wb_lrelu8(act, acc8);
            stage_mat<512>(ws, w3_2 + u * 512, lane);
            cm4<16>(ws, b3_2 + u * 16, s, act, acc4);
        } else {
            const size_t idx3 = (size_t)h * 192 + (size_t)c12;
            cm4<32>(w3_0 + idx3 * 1024, b3_0 + idx3 * 32, s, act, acc8);
            wb_lrelu8(act, acc8);
            cm4<32>(w3_1 + idx3 * 1024, b3_1 + idx3 * 32, s, act, acc8);
            wb_lrelu8(act, acc8);
            cm4<16>(w3_2 + idx3 * 512, b3_2 + idx3 * 16, s, act, acc4);
        }
    }
    const int i3 = argmax4(acc4, s);

    const int inds123 = min(max(inds12 * 10 + (i3 - 3), 0), 1919);

    // ---------------- regressor at predicted leaf ----------------
#pragma unroll
    for (int ii = 0; ii < 8; ii++) act[ii] = x_in[(96 + 8 * s + ii) * HWSZ + base];
    {
        const int sup = inds123 / 5;
        const int fsup = __builtin_amdgcn_readfirstlane(sup);
        if (__all(sup == fsup)) {
            const size_t u = (size_t)h * 384 + (size_t)fsup;
            stage_mat<1024>(ws, wr0 + u * 1024, lane);
            cm4<32>(ws, br0 + u * 32, s, act, acc8);
        } else {
            const size_t idxs = (size_t)h * 384 + (size_t)sup;
            cm4<32>(wr0 + idxs * 1024, br0 + idxs * 32, s, act, acc8);
        }
    }
    wb_lrelu8(act, acc8);

    const size_t idxr = (size_t)h * 1920 + (size_t)inds123;
    const float* __restrict__ wr1r = wr1 + idxr * 32 + 8 * s;
    float4 wa = *reinterpret_cast<const float4*>(wr1r);
    float4 wb = *reinterpret_cast<const float4*>(wr1r + 4);
    float rpart = 0.0f;
    rpart = fmaf(act[0], wa.x, rpart); rpart = fmaf(act[1], wa.y, rpart);
    rpart = fmaf(act[2], wa.z, rpart); rpart = fmaf(act[3], wa.w, rpart);
    rpart = fmaf(act[4], wb.x, rpart); rpart = fmaf(act[5], wb.y, rpart);
    rpart = fmaf(act[6], wb.z, rpart); rpart = fmaf(act[7], wb.w, rpart);
    rpart += __shfl_xor(rpart, 1, 4);
    rpart += __shfl_xor(rpart, 2, 4);
    const float r = rpart + br1[idxr];

    if (s == 0 && valid) {
        float v = ((float)inds123 + r) * (1.0f / 1920.0f);
        out[h * WW + w] = (v - 0.1f) * 1.25f;
    }
}

extern "C" void kernel_launch(void* const* d_in, const int* in_sizes, int n_in,
                              void* d_out, int out_size, void* d_ws, size_t ws_size,
                              hipStream_t stream) {
    const float* p[23];
    for (int i = 0; i < 23; i++) p[i] = (const float*)d_in[i];
    dim3 grid(10, HH);   // 64 pixels per block, 4 lanes per pixel
    regressor_fused<<<grid, 256, 0, stream>>>(
        p[0],
        p[1], p[2], p[3], p[4], p[5], p[6],
        p[7], p[8], p[9], p[10], p[11], p[12],
        p[13], p[14], p[15], p[16], p[17], p[18],
        p[19], p[20], p[21], p[22],
        (float*)d_out);
}